// Round 1
// baseline (6999.535 us; speedup 1.0000x reference)
//
#include <hip/hip_runtime.h>

#define BB 256
#define SS 336
#define HH 512
#define NT 431   // output time steps
#define NU 432   // total cell steps (336 enc + 96 pred)

typedef __attribute__((ext_vector_type(8))) short bf16x8;
typedef __attribute__((ext_vector_type(16))) float f32x16;

// ---------------- ws layout (bytes) ----------------
// wFrag : 4 matrices (lin_whh, lin_wih, quat_whh, quat_wih), fragment-order bf16
//         each 2048*512*2B = 2 MB                              @ 0
// hbuf  : 2 parity * 2 branch * 8rb*32kb*64lane*8 bf16 (256KB) @ 8388608
// cbuf  : 2 branch * 512 col * 256 row f32                     @ 9437184
// M     : [2][2048][4] f32                                     @ 10485760
// bE    : [2][2048] f32                                        @ 10551296
// bP    : [2][2048] f32                                        @ 10567680

__device__ inline unsigned short f2bf(float f) {
    unsigned int u = __float_as_uint(f);
    unsigned int r = (u + 0x7fffu + ((u >> 16) & 1u)) >> 16;
    return (unsigned short)r;
}
__device__ inline float sigm(float x) { return 1.f / (1.f + __expf(-x)); }
__device__ inline float tanh_(float x) { return 2.f / (1.f + __expf(-2.f * x)) - 1.f; }

// Convert the 4 recurrent weight matrices [2048][512] f32 -> bf16 in MFMA
// B-fragment order: [mat][cg(32)][csub(2)][kb(32)][lane(64)][8]
__global__ void k_wfrag(const float* __restrict__ w0, const float* __restrict__ w1,
                        const float* __restrict__ w2, const float* __restrict__ w3,
                        unsigned short* __restrict__ wfrag) {
    int idx = blockIdx.x * 256 + threadIdx.x;      // 0 .. 524287
    int mat = idx >> 17;
    int t = idx & 131071;
    int lane = t & 63;
    int kb = (t >> 6) & 31;
    int csub = (t >> 11) & 1;
    int cg = t >> 12;                               // 0..31
    const float* W = mat == 0 ? w0 : (mat == 1 ? w1 : (mat == 2 ? w2 : w3));
    int n_local = csub * 32 + (lane & 31);          // local gate-col 0..63
    int n = (n_local >> 4) * 512 + cg * 16 + (n_local & 15);  // global gate row
    int k0 = kb * 16 + (lane >> 5) * 8;
    const float* src = W + n * 512 + k0;
    unsigned short us[8];
#pragma unroll
    for (int j = 0; j < 8; ++j) us[j] = f2bf(src[j]);
    int4 v;
    v.x = us[0] | (us[1] << 16); v.y = us[2] | (us[3] << 16);
    v.z = us[4] | (us[5] << 16); v.w = us[6] | (us[7] << 16);
    ((int4*)wfrag)[idx] = v;
}

// M = Wih@We  [2][2048][4], bE = Wih@be + bih + bhh, bP = bih + bhh
__global__ void k_mbias(const float* __restrict__ lin_wih, const float* __restrict__ quat_wih,
                        const float* __restrict__ lin_enc_w, const float* __restrict__ quat_enc_w,
                        const float* __restrict__ lin_enc_b, const float* __restrict__ quat_enc_b,
                        const float* __restrict__ lin_bih, const float* __restrict__ lin_bhh,
                        const float* __restrict__ quat_bih, const float* __restrict__ quat_bhh,
                        float* __restrict__ M, float* __restrict__ bE, float* __restrict__ bP) {
    int gid = blockIdx.x * 256 + threadIdx.x;      // 0..4095
    int branch = gid >> 11;
    int n = gid & 2047;
    int nf = 3 + branch;
    const float* Wih = branch ? quat_wih : lin_wih;
    const float* We  = branch ? quat_enc_w : lin_enc_w;
    const float* be  = branch ? quat_enc_b : lin_enc_b;
    const float* bih = branch ? quat_bih : lin_bih;
    const float* bhh = branch ? quat_bhh : lin_bhh;
    float m[4] = {0.f, 0.f, 0.f, 0.f};
    float bs = 0.f;
    for (int j = 0; j < 512; ++j) {
        float w = Wih[n * 512 + j];
#pragma unroll
        for (int kf = 0; kf < 4; ++kf)
            if (kf < nf) m[kf] += w * We[j * nf + kf];
        bs += w * be[j];
    }
    float* Mp = M + (branch * 2048 + n) * 4;
#pragma unroll
    for (int kf = 0; kf < 4; ++kf) Mp[kf] = m[kf];
    bE[branch * 2048 + n] = bs + bih[n] + bhh[n];
    bP[branch * 2048 + n] = bih[n] + bhh[n];
}

__global__ void k_zero(int4* __restrict__ p) {
    int idx = blockIdx.x * 256 + threadIdx.x;      // 131072 int4 = 2 MB (hbuf + cbuf)
    p[idx] = int4{0, 0, 0, 0};
}

__global__ void k_initout(float* __restrict__ out,
                          const float* __restrict__ lb, const float* __restrict__ qb) {
    int idx = blockIdx.x * 256 + threadIdx.x;      // exactly 772352
    if (idx < BB * NT * 7) {
        int d = idx % 7;
        out[idx] = d < 3 ? lb[d] : qb[d - 3];
    }
}

// One LSTM cell step for both branches.
// grid 256 blocks: branch = blk>>7, rg = (blk>>5)&3 (64-row group), cg = blk&31 (16 h-cols)
__global__ __launch_bounds__(256, 1) void k_step(
    const float* __restrict__ x,
    const unsigned short* __restrict__ wfrag,
    const float* __restrict__ M, const float* __restrict__ bE, const float* __restrict__ bP,
    const float* __restrict__ lin_dec_w, const float* __restrict__ quat_dec_w,
    const unsigned short* __restrict__ hin, unsigned short* __restrict__ hout,
    float* __restrict__ cbuf, float* __restrict__ out,
    int u, int is_enc) {
    __shared__ float g_lds[64 * 65];
    __shared__ float h_tile[64 * 17];
    int tid = threadIdx.x;
    int lane = tid & 63;
    int wv = tid >> 6;
    int rsub = wv & 1, csub = wv >> 1;
    int blk = blockIdx.x;
    int branch = blk >> 7;
    int rg = (blk >> 5) & 3;
    int cg = blk & 31;
    int mat = branch * 2 + (is_enc ? 0 : 1);

    // ---- GEMM: g[64 rows x 64 gcols] = h[64 x 512] @ W_sliceT, fragment loads from global
    const int4* Ap = (const int4*)(hin + branch * 131072) + (rg * 2 + rsub) * 32 * 64 + lane;
    const int4* Bp = (const int4*)(wfrag + (size_t)mat * 1048576) + (cg * 2 + csub) * 32 * 64 + lane;
    f32x16 acc0 = {};
    f32x16 acc1 = {};
#pragma unroll
    for (int kb = 0; kb < 32; kb += 2) {
        int4 a0 = Ap[kb * 64];
        int4 b0 = Bp[kb * 64];
        int4 a1 = Ap[(kb + 1) * 64];
        int4 b1 = Bp[(kb + 1) * 64];
        acc0 = __builtin_amdgcn_mfma_f32_32x32x16_bf16(*(const bf16x8*)&a0, *(const bf16x8*)&b0, acc0, 0, 0, 0);
        acc1 = __builtin_amdgcn_mfma_f32_32x32x16_bf16(*(const bf16x8*)&a1, *(const bf16x8*)&b1, acc1, 0, 0, 0);
    }
    // C layout (32x32): col = lane&31, row = (reg&3) + 8*(reg>>2) + 4*(lane>>5)
    int col_l = csub * 32 + (lane & 31);
    int rbase = rsub * 32 + 4 * (lane >> 5);
#pragma unroll
    for (int r = 0; r < 16; ++r) {
        int row_l = rbase + (r & 3) + 8 * (r >> 2);
        g_lds[row_l * 65 + col_l] = acc0[r] + acc1[r];
    }
    __syncthreads();

    // ---- gates: thread handles row = tid&63, jj = (tid>>6)*4 + p
    int row = tid & 63;
    int b = rg * 64 + row;
    int jbase = tid >> 6;
    int nf = 3 + branch;
    float xv[4] = {0.f, 0.f, 0.f, 0.f};
    if (is_enc) {
        const float* xp = x + (b * SS + u) * 7 + branch * 3;
#pragma unroll
        for (int kf = 0; kf < 4; ++kf)
            if (kf < nf) xv[kf] = xp[kf];
    }
#pragma unroll
    for (int p = 0; p < 4; ++p) {
        int jj = jbase * 4 + p;
        int jcol = cg * 16 + jj;
        float gi = g_lds[row * 65 + jj];
        float gf = g_lds[row * 65 + 16 + jj];
        float gc = g_lds[row * 65 + 32 + jj];
        float go = g_lds[row * 65 + 48 + jj];
        if (is_enc) {
            const float* Mb = M + (size_t)branch * 2048 * 4;
            const float* bEb = bE + branch * 2048;
            {
                const float* mm = Mb + (0 * 512 + jcol) * 4;
                gi += bEb[0 * 512 + jcol] + xv[0] * mm[0] + xv[1] * mm[1] + xv[2] * mm[2] + xv[3] * mm[3];
            }
            {
                const float* mm = Mb + (1 * 512 + jcol) * 4;
                gf += bEb[1 * 512 + jcol] + xv[0] * mm[0] + xv[1] * mm[1] + xv[2] * mm[2] + xv[3] * mm[3];
            }
            {
                const float* mm = Mb + (2 * 512 + jcol) * 4;
                gc += bEb[2 * 512 + jcol] + xv[0] * mm[0] + xv[1] * mm[1] + xv[2] * mm[2] + xv[3] * mm[3];
            }
            {
                const float* mm = Mb + (3 * 512 + jcol) * 4;
                go += bEb[3 * 512 + jcol] + xv[0] * mm[0] + xv[1] * mm[1] + xv[2] * mm[2] + xv[3] * mm[3];
            }
        } else {
            const float* bPb = bP + branch * 2048;
            gi += bPb[jcol];
            gf += bPb[512 + jcol];
            gc += bPb[1024 + jcol];
            go += bPb[1536 + jcol];
        }
        float iv = sigm(gi), fv = sigm(gf), gv = tanh_(gc), ov = sigm(go);
        float cn;
        if (is_enc) {
            float* cp = cbuf + (branch * 512 + jcol) * 256 + b;
            cn = fv * (*cp) + iv * gv;
            *cp = cn;
        } else {
            cn = iv * gv;   // pred steps start from zero state
        }
        h_tile[row * 17 + jj] = ov * tanh_(cn);
    }
    __syncthreads();

    // ---- write h_new (bf16, fragment order) for the next step's A operand
    if (tid < 128) {
        int chunk = tid >> 6;
        int l = tid & 63;
        int row_l = chunk * 32 + (l & 31);
        int jh = (l >> 5) * 8;
        unsigned short us[8];
#pragma unroll
        for (int j = 0; j < 8; ++j) us[j] = f2bf(h_tile[row_l * 17 + jh + j]);
        int4 v;
        v.x = us[0] | (us[1] << 16); v.y = us[2] | (us[3] << 16);
        v.z = us[4] | (us[5] << 16); v.w = us[6] | (us[7] << 16);
        int rb = rg * 2 + chunk;
        ((int4*)(hout + branch * 131072))[(rb * 32 + cg) * 64 + l] = v;
    }
    // ---- fused decoder: partial dot over this block's 16 h-cols, atomic accumulate
    if (u >= 1) {
        int d = tid >> 6;
        if (d < nf) {
            const float* wd = (branch ? quat_dec_w : lin_dec_w) + d * 512 + cg * 16;
            float s = 0.f;
#pragma unroll
            for (int j2 = 0; j2 < 16; ++j2) s += h_tile[row * 17 + j2] * wd[j2];
            unsafeAtomicAdd(out + ((size_t)b * NT + (u - 1)) * 7 + branch * 3 + d, s);
        }
    }
}

extern "C" void kernel_launch(void* const* d_in, const int* in_sizes, int n_in,
                              void* d_out, int out_size, void* d_ws, size_t ws_size,
                              hipStream_t stream) {
    const float* x          = (const float*)d_in[0];
    const float* lin_enc_w  = (const float*)d_in[1];
    const float* lin_enc_b  = (const float*)d_in[2];
    const float* quat_enc_w = (const float*)d_in[3];
    const float* quat_enc_b = (const float*)d_in[4];
    const float* lin_wih    = (const float*)d_in[5];
    const float* lin_whh    = (const float*)d_in[6];
    const float* lin_bih    = (const float*)d_in[7];
    const float* lin_bhh    = (const float*)d_in[8];
    const float* quat_wih   = (const float*)d_in[9];
    const float* quat_whh   = (const float*)d_in[10];
    const float* quat_bih   = (const float*)d_in[11];
    const float* quat_bhh   = (const float*)d_in[12];
    const float* lin_dec_w  = (const float*)d_in[13];
    const float* lin_dec_b  = (const float*)d_in[14];
    const float* quat_dec_w = (const float*)d_in[15];
    const float* quat_dec_b = (const float*)d_in[16];
    float* out = (float*)d_out;
    char* ws = (char*)d_ws;

    unsigned short* wfrag = (unsigned short*)(ws + 0);
    unsigned short* hbuf  = (unsigned short*)(ws + 8388608ull);
    float* cbuf = (float*)(ws + 9437184ull);
    float* M    = (float*)(ws + 10485760ull);
    float* bE   = (float*)(ws + 10551296ull);
    float* bP   = (float*)(ws + 10567680ull);

    k_wfrag<<<2048, 256, 0, stream>>>(lin_whh, lin_wih, quat_whh, quat_wih, wfrag);
    k_mbias<<<16, 256, 0, stream>>>(lin_wih, quat_wih, lin_enc_w, quat_enc_w,
                                    lin_enc_b, quat_enc_b, lin_bih, lin_bhh,
                                    quat_bih, quat_bhh, M, bE, bP);
    k_zero<<<512, 256, 0, stream>>>((int4*)(ws + 8388608ull));   // hbuf (both parities) + cbuf
    k_initout<<<3017, 256, 0, stream>>>(out, lin_dec_b, quat_dec_b);

    for (int u = 0; u < NU; ++u) {
        const unsigned short* hin = hbuf + (size_t)(u & 1) * 262144;
        unsigned short* hout      = hbuf + (size_t)((u + 1) & 1) * 262144;
        k_step<<<256, 256, 0, stream>>>(x, wfrag, M, bE, bP, lin_dec_w, quat_dec_w,
                                        hin, hout, cbuf, out, u, u < SS ? 1 : 0);
    }
}